// Round 1
// baseline (3263.787 us; speedup 1.0000x reference)
//
#include <hip/hip_runtime.h>
#include <math.h>

// ---------------------------------------------------------------------------
// Fused conv1(3->64,3x3,s2,SAME) + relu + conv2(64->64,3x3,s2,SAME) + relu
//       + 8x8 mean-pool + attention MLP + threshold  ->  mask[B*16]
// One block per (batch, patch). conv1 tile kept in LDS (never hits HBM).
// SAME stride-2 padding for 128->64 and 64->32 is (pad_lo=0, pad_hi=1).
// ---------------------------------------------------------------------------
__global__ __launch_bounds__(256, 2)
void conv_attn_kernel(const float* __restrict__ images,
                      const float* __restrict__ cw1, const float* __restrict__ cb1,
                      const float* __restrict__ cw2, const float* __restrict__ cb2,
                      const float* __restrict__ aw1, const float* __restrict__ ab1,
                      const float* __restrict__ aw2, const float* __restrict__ ab2,
                      const float* __restrict__ thr, float* __restrict__ mask_out)
{
    __shared__ float c1[64][17][18];   // 78336 B: conv1 activations for this patch
    __shared__ float tok[64];
    __shared__ float ured[32];

    const int blk   = blockIdx.x;      // 0..8191
    const int b     = blk >> 4;
    const int patch = blk & 15;
    const int pr = patch >> 2, pc = patch & 3;
    const int tid = threadIdx.x;
    const float* img = images + (size_t)b * (3 * 128 * 128);

    // ---- conv1 + relu into LDS tile: conv1 rows 16*pr..16*pr+16 (17x17) ----
    for (int p = tid; p < 289; p += 256) {
        const int ty = p / 17, tx = p % 17;
        const int oy = 16 * pr + ty, ox = 16 * pc + tx;
        float acc[64];
        if (oy < 64 && ox < 64) {
            float iv[27];
            #pragma unroll
            for (int ic = 0; ic < 3; ++ic)
            #pragma unroll
            for (int kh = 0; kh < 3; ++kh)
            #pragma unroll
            for (int kw = 0; kw < 3; ++kw) {
                const int iy = 2 * oy + kh, ix = 2 * ox + kw;  // pad_lo=0, pad_hi=1
                float v = 0.f;
                if (iy < 128 && ix < 128) v = img[ic * 16384 + iy * 128 + ix];
                iv[(ic * 3 + kh) * 3 + kw] = v;
            }
            #pragma unroll
            for (int oc = 0; oc < 64; ++oc) {
                float a = cb1[oc];
                #pragma unroll
                for (int k = 0; k < 27; ++k) a = fmaf(iv[k], cw1[oc * 27 + k], a);
                acc[oc] = fmaxf(a, 0.f);
            }
        } else {  // conv2's SAME padding row/col (conv1 coord 64) -> zeros
            #pragma unroll
            for (int oc = 0; oc < 64; ++oc) acc[oc] = 0.f;
        }
        #pragma unroll
        for (int oc = 0; oc < 64; ++oc) c1[oc][ty][tx] = acc[oc];
    }
    __syncthreads();

    // ---- conv2 + relu + 8x8 mean pool ----
    // wave w -> output channels [16w,16w+16); lane -> spatial (sy,sx) in 8x8
    const int wid  = __builtin_amdgcn_readfirstlane(tid >> 6);
    const int lane = tid & 63;
    const int sy = lane >> 3, sx = lane & 7;

    float acc2[16];
    #pragma unroll
    for (int o = 0; o < 16; ++o) acc2[o] = cb2[wid * 16 + o];

    #pragma unroll 2
    for (int ic = 0; ic < 64; ++ic) {
        float cv[9];
        #pragma unroll
        for (int kh = 0; kh < 3; ++kh)
        #pragma unroll
        for (int kw = 0; kw < 3; ++kw)
            cv[kh * 3 + kw] = c1[ic][2 * sy + kh][2 * sx + kw];
        #pragma unroll
        for (int o = 0; o < 16; ++o) {
            const int oc = wid * 16 + o;
            float a = acc2[o];
            #pragma unroll
            for (int k9 = 0; k9 < 9; ++k9)
                a = fmaf(cv[k9], cw2[(oc * 64 + ic) * 9 + k9], a);
            acc2[o] = a;
        }
    }

    // relu then mean over the 64 spatial lanes, per channel
    #pragma unroll
    for (int o = 0; o < 16; ++o) {
        float v = fmaxf(acc2[o], 0.f);
        v += __shfl_xor(v, 32, 64);
        v += __shfl_xor(v, 16, 64);
        v += __shfl_xor(v,  8, 64);
        v += __shfl_xor(v,  4, 64);
        v += __shfl_xor(v,  2, 64);
        v += __shfl_xor(v,  1, 64);
        if (lane == o) tok[wid * 16 + o] = v * (1.f / 64.f);
    }
    __syncthreads();

    // ---- attention MLP 64->32->1, sigmoid, threshold ----
    if (tid < 32) {
        float u = ab1[tid];
        #pragma unroll 8
        for (int k = 0; k < 64; ++k) u = fmaf(aw1[tid * 64 + k], tok[k], u);
        ured[tid] = fmaxf(u, 0.f);
    }
    __syncthreads();
    if (tid == 0) {
        float x = ab2[0];
        #pragma unroll 8
        for (int j = 0; j < 32; ++j) x = fmaf(aw2[j], ured[j], x);
        const float score = 1.f / (1.f + expf(-x));
        mask_out[blk] = (score > thr[0]) ? 1.f : 0.f;   // forward value of ST mask
    }
}

// ---------------------------------------------------------------------------
// Tiled f32 GEMM: C = act(A(MxK) * W(NxK)^T + bias) [* mask | * (1-mask)] [+= C]
// 256 threads as 16x16; thread computes TM x TN. BK=16. All K here are %16==0,
// all M are %BM==0; only N needs guarding (N=10 head).
// ---------------------------------------------------------------------------
template<int BM, int BN, int TM, int TN, bool RELU, int MMODE, bool ACCUM>
__global__ __launch_bounds__(256, 2)
void gemm_kernel(const float* __restrict__ A, const float* __restrict__ W,
                 const float* __restrict__ bias, const float* __restrict__ mask,
                 float* __restrict__ C, int M, int N, int K)
{
    constexpr int BK  = 16;
    constexpr int LDA = BM + 4;   // rows stay 16B-aligned, <=2-way banks
    constexpr int LDB = BN + 4;
    __shared__ float As[BK][LDA];
    __shared__ float Ws[BK][LDB];

    const int tid = threadIdx.x;
    const int tx = tid & 15;      // n
    const int ty = tid >> 4;      // m
    const int bm = blockIdx.x * BM;
    const int bn = blockIdx.y * BN;

    float acc[TM][TN];
    #pragma unroll
    for (int i = 0; i < TM; ++i)
        #pragma unroll
        for (int j = 0; j < TN; ++j) acc[i][j] = 0.f;

    constexpr int ACH = (BM * BK) / (4 * 256);  // float4 chunks/thread (A)
    constexpr int BCH = (BN * BK) / (4 * 256);  // float4 chunks/thread (W)

    for (int k0 = 0; k0 < K; k0 += BK) {
        #pragma unroll
        for (int q = 0; q < ACH; ++q) {
            const int c = tid + q * 256;
            const int m = c >> 2;
            const int kq = (c & 3) * 4;
            const float4 v = *(const float4*)&A[(size_t)(bm + m) * K + k0 + kq];
            As[kq + 0][m] = v.x; As[kq + 1][m] = v.y;
            As[kq + 2][m] = v.z; As[kq + 3][m] = v.w;
        }
        #pragma unroll
        for (int q = 0; q < BCH; ++q) {
            const int c = tid + q * 256;
            const int n = c >> 2;
            const int kq = (c & 3) * 4;
            float4 v = make_float4(0.f, 0.f, 0.f, 0.f);
            if (bn + n < N) v = *(const float4*)&W[(size_t)(bn + n) * K + k0 + kq];
            Ws[kq + 0][n] = v.x; Ws[kq + 1][n] = v.y;
            Ws[kq + 2][n] = v.z; Ws[kq + 3][n] = v.w;
        }
        __syncthreads();

        #pragma unroll
        for (int k = 0; k < BK; ++k) {
            float av[TM], bv[TN];
            {
                const float4 t0 = *(const float4*)&As[k][ty * TM];
                av[0] = t0.x; av[1] = t0.y; av[2] = t0.z; av[3] = t0.w;
                if constexpr (TM == 8) {
                    const float4 t1 = *(const float4*)&As[k][ty * TM + 4];
                    av[4] = t1.x; av[5] = t1.y; av[6] = t1.z; av[7] = t1.w;
                }
            }
            {
                const float4 t0 = *(const float4*)&Ws[k][tx * TN];
                bv[0] = t0.x; bv[1] = t0.y; bv[2] = t0.z; bv[3] = t0.w;
            }
            #pragma unroll
            for (int i = 0; i < TM; ++i)
                #pragma unroll
                for (int j = 0; j < TN; ++j)
                    acc[i][j] = fmaf(av[i], bv[j], acc[i][j]);
        }
        __syncthreads();
    }

    #pragma unroll
    for (int i = 0; i < TM; ++i) {
        const int row = bm + ty * TM + i;
        float mv = 1.f;
        if (MMODE == 1) mv = mask[row];
        if (MMODE == 2) mv = 1.f - mask[row];
        #pragma unroll
        for (int j = 0; j < TN; ++j) {
            const int col = bn + tx * TN + j;
            if (col < N) {
                float v = acc[i][j] + bias[col];
                if (RELU)  v = fmaxf(v, 0.f);
                if (MMODE) v *= mv;
                const size_t o = (size_t)row * N + col;
                C[o] = ACCUM ? (C[o] + v) : v;
            }
        }
    }
}

// ---------------------------------------------------------------------------
extern "C" void kernel_launch(void* const* d_in, const int* in_sizes, int n_in,
                              void* d_out, int out_size, void* d_ws, size_t ws_size,
                              hipStream_t stream)
{
    (void)in_sizes; (void)n_in; (void)out_size; (void)ws_size;
    const float* images = (const float*)d_in[0];
    const float* patches= (const float*)d_in[1];
    const float* cw1 = (const float*)d_in[2];
    const float* cb1 = (const float*)d_in[3];
    const float* cw2 = (const float*)d_in[4];
    const float* cb2 = (const float*)d_in[5];
    const float* aw1 = (const float*)d_in[6];
    const float* ab1 = (const float*)d_in[7];
    const float* aw2 = (const float*)d_in[8];
    const float* ab2 = (const float*)d_in[9];
    const float* thr = (const float*)d_in[10];
    const float* bw1 = (const float*)d_in[11];
    const float* bb1 = (const float*)d_in[12];
    const float* bw2 = (const float*)d_in[13];
    const float* bb2 = (const float*)d_in[14];
    const float* bw3 = (const float*)d_in[15];
    const float* bb3 = (const float*)d_in[16];
    const float* bwo = (const float*)d_in[17];
    const float* bbo = (const float*)d_in[18];
    const float* sw1 = (const float*)d_in[19];
    const float* sb1 = (const float*)d_in[20];
    const float* swo = (const float*)d_in[21];
    const float* sbo = (const float*)d_in[22];
    const float* gw  = (const float*)d_in[23];
    const float* gb  = (const float*)d_in[24];
    const float* hw1 = (const float*)d_in[25];
    const float* hb1 = (const float*)d_in[26];
    const float* hw2 = (const float*)d_in[27];
    const float* hb2 = (const float*)d_in[28];
    float* out = (float*)d_out;
    float* ws  = (float*)d_ws;

    // workspace layout (floats): total ~36.8 MB
    float* mask = ws;                      // 8192
    float* HA   = ws + 8192;               // 8192*512
    float* HB   = HA + 8192 * 512;         // 8192*512
    float* CMB  = HB + 8192 * 512;         // 8192*128
    float* G    = CMB + 8192 * 128;        // 512*256
    float* T    = G + 512 * 256;           // 512*128

    // router mask (exact f32 score chain)
    conv_attn_kernel<<<8192, 256, 0, stream>>>(images, cw1, cb1, cw2, cb2,
                                               aw1, ab1, aw2, ab2, thr, mask);

    // big MLP: pf -> 512 -> 512 -> 512 -> 128 (masked)
    gemm_kernel<128,64,8,4,true ,0,false><<<dim3(64,8), 256, 0, stream>>>(patches, bw1, bb1, nullptr, HA, 8192, 512, 3072);
    gemm_kernel<128,64,8,4,true ,0,false><<<dim3(64,8), 256, 0, stream>>>(HA,      bw2, bb2, nullptr, HB, 8192, 512, 512);
    gemm_kernel<128,64,8,4,true ,0,false><<<dim3(64,8), 256, 0, stream>>>(HB,      bw3, bb3, nullptr, HA, 8192, 512, 512);
    gemm_kernel<128,64,8,4,false,1,false><<<dim3(64,2), 256, 0, stream>>>(HA,      bwo, bbo, mask,    CMB, 8192, 128, 512);

    // small MLP: pf -> 64 -> 128 ((1-mask), accumulated into CMB)
    gemm_kernel<64,64,4,4,true ,0,false><<<dim3(128,1), 256, 0, stream>>>(patches, sw1, sb1, nullptr, HB, 8192, 64, 3072);
    gemm_kernel<128,64,8,4,false,2,true ><<<dim3(64,2), 256, 0, stream>>>(HB,      swo, sbo, mask,    CMB, 8192, 128, 64);

    // aggregator (B,2048)->256, head 256->128->10
    gemm_kernel<64,64,4,4,false,0,false><<<dim3(8,4), 256, 0, stream>>>(CMB, gw,  gb,  nullptr, G,   512, 256, 2048);
    gemm_kernel<64,64,4,4,true ,0,false><<<dim3(8,2), 256, 0, stream>>>(G,   hw1, hb1, nullptr, T,   512, 128, 256);
    gemm_kernel<64,64,4,4,false,0,false><<<dim3(8,1), 256, 0, stream>>>(T,   hw2, hb2, nullptr, out, 512, 10,  128);
}

// Round 4
// 2836.510 us; speedup vs baseline: 1.1506x; 1.1506x over previous
//
#include <hip/hip_runtime.h>
#include <math.h>

// ---------------------------------------------------------------------------
// Fused conv1(3->64,3x3,s2,SAME) + relu + conv2(64->64,3x3,s2,SAME) + relu
//       + 8x8 mean-pool + attention MLP + threshold  ->  mask[B*16]
// One block per (batch, patch). Channel-chunked (4 x 16ch) so the conv1 LDS
// tile is 21.8 KB -> 4 blocks/CU. Parity-split x layout makes conv2's
// stride-2 LDS reads conflict-free: bank = (8*sy + sx) % 32, bijective.
// ---------------------------------------------------------------------------
__global__ __launch_bounds__(256, 4)
void conv_attn_kernel(const float* __restrict__ images,
                      const float* __restrict__ cw1, const float* __restrict__ cb1,
                      const float* __restrict__ cw2, const float* __restrict__ cb2,
                      const float* __restrict__ aw1, const float* __restrict__ ab1,
                      const float* __restrict__ aw2, const float* __restrict__ ab2,
                      const float* __restrict__ thr, float* __restrict__ mask_out)
{
    // [oc' 0..15][y 0..16][parity 0..1][x' 0..9] : oc stride 340, y stride 20
    __shared__ float c1s[16 * 17 * 20];   // 21760 B
    __shared__ float tok[64];
    __shared__ float ured[32];

    const int blk   = blockIdx.x;      // 0..8191
    const int b     = blk >> 4;
    const int patch = blk & 15;
    const int pr = patch >> 2, pc = patch & 3;
    const int tid = threadIdx.x;
    const float* img = images + (size_t)b * (3 * 128 * 128);

    const int wid  = __builtin_amdgcn_readfirstlane(tid >> 6);
    const int lane = tid & 63;
    const int sy = lane >> 3, sx = lane & 7;

    float acc2[16];
    #pragma unroll
    for (int o = 0; o < 16; ++o) acc2[o] = cb2[wid * 16 + o];

    for (int chunk = 0; chunk < 4; ++chunk) {
        // ---- conv1 + relu for oc in [16*chunk, 16*chunk+16) into LDS ----
        for (int p = tid; p < 289; p += 256) {
            const int ty = p / 17, tx = p % 17;
            const int oy = 16 * pr + ty, ox = 16 * pc + tx;
            float vals[16];
            if (oy < 64 && ox < 64) {
                float iv[27];
                #pragma unroll
                for (int ic = 0; ic < 3; ++ic)
                #pragma unroll
                for (int kh = 0; kh < 3; ++kh)
                #pragma unroll
                for (int kw = 0; kw < 3; ++kw) {
                    const int iy = 2 * oy + kh, ix = 2 * ox + kw;  // pad_lo=0
                    float v = 0.f;
                    if (iy < 128 && ix < 128) v = img[ic * 16384 + iy * 128 + ix];
                    iv[(ic * 3 + kh) * 3 + kw] = v;
                }
                #pragma unroll
                for (int o = 0; o < 16; ++o) {
                    const int oc = chunk * 16 + o;
                    float a = cb1[oc];
                    #pragma unroll
                    for (int k = 0; k < 27; ++k) a = fmaf(iv[k], cw1[oc * 27 + k], a);
                    vals[o] = fmaxf(a, 0.f);
                }
            } else {  // conv2 SAME padding (coord 64) -> zeros
                #pragma unroll
                for (int o = 0; o < 16; ++o) vals[o] = 0.f;
            }
            const int base = ty * 20 + (tx & 1) * 10 + (tx >> 1);
            #pragma unroll
            for (int o = 0; o < 16; ++o) c1s[o * 340 + base] = vals[o];
        }
        __syncthreads();

        // ---- conv2 partial sum over these 16 input channels ----
        // lane -> spatial (sy,sx); wave -> 16 output channels
        #pragma unroll 4
        for (int icp = 0; icp < 16; ++icp) {
            float cv[9];
            #pragma unroll
            for (int kh = 0; kh < 3; ++kh)
            #pragma unroll
            for (int kw = 0; kw < 3; ++kw)
                cv[kh * 3 + kw] = c1s[icp * 340 + (2 * sy + kh) * 20
                                      + (kw & 1) * 10 + sx + (kw >> 1)];
            const int ic = chunk * 16 + icp;
            #pragma unroll
            for (int o = 0; o < 16; ++o) {
                const int oc = wid * 16 + o;
                float a = acc2[o];
                #pragma unroll
                for (int k9 = 0; k9 < 9; ++k9)
                    a = fmaf(cv[k9], cw2[(oc * 64 + ic) * 9 + k9], a);
                acc2[o] = a;
            }
        }
        __syncthreads();   // before next chunk overwrites c1s
    }

    // ---- relu then mean over the 64 spatial lanes, per channel ----
    #pragma unroll
    for (int o = 0; o < 16; ++o) {
        float v = fmaxf(acc2[o], 0.f);
        v += __shfl_xor(v, 32, 64);
        v += __shfl_xor(v, 16, 64);
        v += __shfl_xor(v,  8, 64);
        v += __shfl_xor(v,  4, 64);
        v += __shfl_xor(v,  2, 64);
        v += __shfl_xor(v,  1, 64);
        if (lane == o) tok[wid * 16 + o] = v * (1.f / 64.f);
    }
    __syncthreads();

    // ---- attention MLP 64->32->1, sigmoid, threshold ----
    if (tid < 32) {
        float u = ab1[tid];
        #pragma unroll 8
        for (int k = 0; k < 64; ++k) u = fmaf(aw1[tid * 64 + k], tok[k], u);
        ured[tid] = fmaxf(u, 0.f);
    }
    __syncthreads();
    if (tid == 0) {
        float x = ab2[0];
        #pragma unroll 8
        for (int j = 0; j < 32; ++j) x = fmaf(aw2[j], ured[j], x);
        const float score = 1.f / (1.f + expf(-x));
        mask_out[blk] = (score > thr[0]) ? 1.f : 0.f;   // forward value of ST mask
    }
}

// ---------------------------------------------------------------------------
// Tiled f32 GEMM: C = act(A(MxK) * W(NxK)^T + bias) [* mask | * (1-mask)] [+= C]
// 256 threads as 16x16; thread computes TM x TN. BK=16. All K here are %16==0,
// all M are %BM==0; only N needs guarding (N=10 head).
// ---------------------------------------------------------------------------
template<int BM, int BN, int TM, int TN, bool RELU, int MMODE, bool ACCUM>
__global__ __launch_bounds__(256, 2)
void gemm_kernel(const float* __restrict__ A, const float* __restrict__ W,
                 const float* __restrict__ bias, const float* __restrict__ mask,
                 float* __restrict__ C, int M, int N, int K)
{
    constexpr int BK  = 16;
    constexpr int LDA = BM + 4;   // rows stay 16B-aligned
    constexpr int LDB = BN + 4;
    __shared__ float As[BK][LDA];
    __shared__ float Ws[BK][LDB];

    const int tid = threadIdx.x;
    const int tx = tid & 15;      // n
    const int ty = tid >> 4;      // m
    const int bm = blockIdx.x * BM;
    const int bn = blockIdx.y * BN;

    float acc[TM][TN];
    #pragma unroll
    for (int i = 0; i < TM; ++i)
        #pragma unroll
        for (int j = 0; j < TN; ++j) acc[i][j] = 0.f;

    constexpr int ACH = (BM * BK) / (4 * 256);  // float4 chunks/thread (A)
    constexpr int BCH = (BN * BK) / (4 * 256);  // float4 chunks/thread (W)

    for (int k0 = 0; k0 < K; k0 += BK) {
        #pragma unroll
        for (int q = 0; q < ACH; ++q) {
            const int c = tid + q * 256;
            const int m = c >> 2;
            const int kq = (c & 3) * 4;
            const float4 v = *(const float4*)&A[(size_t)(bm + m) * K + k0 + kq];
            As[kq + 0][m] = v.x; As[kq + 1][m] = v.y;
            As[kq + 2][m] = v.z; As[kq + 3][m] = v.w;
        }
        #pragma unroll
        for (int q = 0; q < BCH; ++q) {
            const int c = tid + q * 256;
            const int n = c >> 2;
            const int kq = (c & 3) * 4;
            float4 v = make_float4(0.f, 0.f, 0.f, 0.f);
            if (bn + n < N) v = *(const float4*)&W[(size_t)(bn + n) * K + k0 + kq];
            Ws[kq + 0][n] = v.x; Ws[kq + 1][n] = v.y;
            Ws[kq + 2][n] = v.z; Ws[kq + 3][n] = v.w;
        }
        __syncthreads();

        #pragma unroll
        for (int k = 0; k < BK; ++k) {
            float av[TM], bv[TN];
            {
                const float4 t0 = *(const float4*)&As[k][ty * TM];
                av[0] = t0.x; av[1] = t0.y; av[2] = t0.z; av[3] = t0.w;
                if constexpr (TM == 8) {
                    const float4 t1 = *(const float4*)&As[k][ty * TM + 4];
                    av[4] = t1.x; av[5] = t1.y; av[6] = t1.z; av[7] = t1.w;
                }
            }
            {
                const float4 t0 = *(const float4*)&Ws[k][tx * TN];
                bv[0] = t0.x; bv[1] = t0.y; bv[2] = t0.z; bv[3] = t0.w;
                if constexpr (TN == 8) {
                    const float4 t1 = *(const float4*)&Ws[k][tx * TN + 4];
                    bv[4] = t1.x; bv[5] = t1.y; bv[6] = t1.z; bv[7] = t1.w;
                }
            }
            #pragma unroll
            for (int i = 0; i < TM; ++i)
                #pragma unroll
                for (int j = 0; j < TN; ++j)
                    acc[i][j] = fmaf(av[i], bv[j], acc[i][j]);
        }
        __syncthreads();
    }

    #pragma unroll
    for (int i = 0; i < TM; ++i) {
        const int row = bm + ty * TM + i;
        float mv = 1.f;
        if (MMODE == 1) mv = mask[row];
        if (MMODE == 2) mv = 1.f - mask[row];
        #pragma unroll
        for (int j = 0; j < TN; ++j) {
            const int col = bn + tx * TN + j;
            if (col < N) {
                float v = acc[i][j] + bias[col];
                if (RELU)  v = fmaxf(v, 0.f);
                if (MMODE) v *= mv;
                const size_t o = (size_t)row * N + col;
                C[o] = ACCUM ? (C[o] + v) : v;
            }
        }
    }
}

// ---------------------------------------------------------------------------
extern "C" void kernel_launch(void* const* d_in, const int* in_sizes, int n_in,
                              void* d_out, int out_size, void* d_ws, size_t ws_size,
                              hipStream_t stream)
{
    (void)in_sizes; (void)n_in; (void)out_size; (void)ws_size;
    const float* images = (const float*)d_in[0];
    const float* patches= (const float*)d_in[1];
    const float* cw1 = (const float*)d_in[2];
    const float* cb1 = (const float*)d_in[3];
    const float* cw2 = (const float*)d_in[4];
    const float* cb2 = (const float*)d_in[5];
    const float* aw1 = (const float*)d_in[6];
    const float* ab1 = (const float*)d_in[7];
    const float* aw2 = (const float*)d_in[8];
    const float* ab2 = (const float*)d_in[9];
    const float* thr = (const float*)d_in[10];
    const float* bw1 = (const float*)d_in[11];
    const float* bb1 = (const float*)d_in[12];
    const float* bw2 = (const float*)d_in[13];
    const float* bb2 = (const float*)d_in[14];
    const float* bw3 = (const float*)d_in[15];
    const float* bb3 = (const float*)d_in[16];
    const float* bwo = (const float*)d_in[17];
    const float* bbo = (const float*)d_in[18];
    const float* sw1 = (const float*)d_in[19];
    const float* sb1 = (const float*)d_in[20];
    const float* swo = (const float*)d_in[21];
    const float* sbo = (const float*)d_in[22];
    const float* gw  = (const float*)d_in[23];
    const float* gb  = (const float*)d_in[24];
    const float* hw1 = (const float*)d_in[25];
    const float* hb1 = (const float*)d_in[26];
    const float* hw2 = (const float*)d_in[27];
    const float* hb2 = (const float*)d_in[28];
    float* out = (float*)d_out;
    float* ws  = (float*)d_ws;

    // workspace layout (floats): total ~36.8 MB
    float* mask = ws;                      // 8192
    float* HA   = ws + 8192;               // 8192*512
    float* HB   = HA + 8192 * 512;         // 8192*512
    float* CMB  = HB + 8192 * 512;         // 8192*128
    float* G    = CMB + 8192 * 128;        // 512*256
    float* T    = G + 512 * 256;           // 512*128

    // router mask (exact f32 score chain)
    conv_attn_kernel<<<8192, 256, 0, stream>>>(images, cw1, cb1, cw2, cb2,
                                               aw1, ab1, aw2, ab2, thr, mask);

    // big MLP: pf -> 512 -> 512 -> 512 -> 128 (masked)
    gemm_kernel<128,128,8,8,true ,0,false><<<dim3(64,4), 256, 0, stream>>>(patches, bw1, bb1, nullptr, HA, 8192, 512, 3072);
    gemm_kernel<128,128,8,8,true ,0,false><<<dim3(64,4), 256, 0, stream>>>(HA,      bw2, bb2, nullptr, HB, 8192, 512, 512);
    gemm_kernel<128,128,8,8,true ,0,false><<<dim3(64,4), 256, 0, stream>>>(HB,      bw3, bb3, nullptr, HA, 8192, 512, 512);
    gemm_kernel<128,128,8,8,false,1,false><<<dim3(64,1), 256, 0, stream>>>(HA,      bwo, bbo, mask,    CMB, 8192, 128, 512);

    // small MLP: pf -> 64 -> 128 ((1-mask), accumulated into CMB)
    gemm_kernel<128,64,8,4,true ,0,false><<<dim3(64,1), 256, 0, stream>>>(patches, sw1, sb1, nullptr, HB, 8192, 64, 3072);
    gemm_kernel<128,128,8,8,false,2,true ><<<dim3(64,1), 256, 0, stream>>>(HB,      swo, sbo, mask,    CMB, 8192, 128, 64);

    // aggregator (B,2048)->256, head 256->128->10
    gemm_kernel<64,64,4,4,false,0,false><<<dim3(8,4), 256, 0, stream>>>(CMB, gw,  gb,  nullptr, G,   512, 256, 2048);
    gemm_kernel<64,64,4,4,true ,0,false><<<dim3(8,2), 256, 0, stream>>>(G,   hw1, hb1, nullptr, T,   512, 128, 256);
    gemm_kernel<64,64,4,4,false,0,false><<<dim3(8,1), 256, 0, stream>>>(T,   hw2, hb2, nullptr, out, 512, 10,  128);
}

// Round 7
// 2032.257 us; speedup vs baseline: 1.6060x; 1.3957x over previous
//
#include <hip/hip_runtime.h>
#include <math.h>

// ---------------------------------------------------------------------------
// Fused conv1(3->64,3x3,s2,SAME) + relu + conv2(64->64,3x3,s2,SAME) + relu
//       + 8x8 mean-pool + attention MLP + threshold  ->  mask[B*16]
// One block per (batch, patch).
//  - input tile (35x35x3) staged once in LDS, parity-split in x -> conv1 has
//    zero global traffic / zero bounds checks in its inner loop.
//  - channel-chunked (4 x 16ch): c1s tile 21.8 KB; total LDS 37.3 KB -> 4 blk/CU.
//  - weights accessed as wave-uniform bases + compile-time offsets in
//    contiguous runs -> compiler emits batched s_load (SMEM pipe), keeping
//    the VALU for FMAs. FMA accumulation order identical to previous rounds.
// ---------------------------------------------------------------------------
__global__ __launch_bounds__(256, 4)
void conv_attn_kernel(const float* __restrict__ images,
                      const float* __restrict__ cw1, const float* __restrict__ cb1,
                      const float* __restrict__ cw2, const float* __restrict__ cb2,
                      const float* __restrict__ aw1, const float* __restrict__ ab1,
                      const float* __restrict__ aw2, const float* __restrict__ ab2,
                      const float* __restrict__ thr, float* __restrict__ mask_out)
{
    // input tile: [c 0..2][y 0..34][parity 0..1][x' 0..17] : c stride 1260, y stride 36
    __shared__ float in_s[3 * 35 * 36];          // 15120 B
    // conv1 out:  [oc' 0..15][y 0..16][parity 0..1][x' 0..9] : oc stride 340, y stride 20
    __shared__ float c1s[16 * 17 * 20];          // 21760 B
    __shared__ float tok[64];
    __shared__ float ured[32];

    const int blk   = blockIdx.x;      // 0..8191
    const int b     = blk >> 4;
    const int patch = blk & 15;
    const int pr = patch >> 2, pc = patch & 3;
    const int tid = threadIdx.x;
    const float* img = images + (size_t)b * (3 * 128 * 128);

    const int wid  = __builtin_amdgcn_readfirstlane(tid >> 6);
    const int lane = tid & 63;
    const int sy = lane >> 3, sx = lane & 7;

    // ---- stage input tile (rows 32pr..32pr+34, cols 32pc..32pc+34), OOB=0 ----
    for (int idx = tid; idx < 3 * 35 * 35; idx += 256) {
        const int c   = idx / 1225;
        const int rem = idx - c * 1225;
        const int y   = rem / 35;
        const int x   = rem - y * 35;
        const int gy  = 32 * pr + y, gx = 32 * pc + x;
        float v = 0.f;
        if (gy < 128 && gx < 128) v = img[c * 16384 + gy * 128 + gx];
        in_s[c * 1260 + y * 36 + (x & 1) * 18 + (x >> 1)] = v;
    }
    __syncthreads();

    float acc2[16];
    #pragma unroll
    for (int o = 0; o < 16; ++o) acc2[o] = cb2[wid * 16 + o];

    for (int chunk = 0; chunk < 4; ++chunk) {
        const float* wb1 = cw1 + chunk * 16 * 27;    // wave-uniform base
        const float* cb1c = cb1 + chunk * 16;

        // ---- conv1 + relu for oc in [16*chunk, 16*chunk+16) into LDS ----
        for (int p = tid; p < 289; p += 256) {
            const int ty = p / 17, tx = p % 17;
            const int oy = 16 * pr + ty, ox = 16 * pc + tx;
            float vals[16];
            if (oy < 64 && ox < 64) {
                float iv[27];
                #pragma unroll
                for (int ic = 0; ic < 3; ++ic)
                #pragma unroll
                for (int kh = 0; kh < 3; ++kh)
                #pragma unroll
                for (int kw = 0; kw < 3; ++kw)
                    iv[(ic * 3 + kh) * 3 + kw] =
                        in_s[ic * 1260 + (2 * ty + kh) * 36 + (kw & 1) * 18 + tx + (kw >> 1)];
                #pragma unroll
                for (int o = 0; o < 16; ++o) {
                    float a = cb1c[o];
                    #pragma unroll
                    for (int k = 0; k < 27; ++k) a = fmaf(iv[k], wb1[o * 27 + k], a);
                    vals[o] = fmaxf(a, 0.f);
                }
            } else {  // conv2 SAME padding (coord 64) -> zeros
                #pragma unroll
                for (int o = 0; o < 16; ++o) vals[o] = 0.f;
            }
            const int base = ty * 20 + (tx & 1) * 10 + (tx >> 1);
            #pragma unroll
            for (int o = 0; o < 16; ++o) c1s[o * 340 + base] = vals[o];
        }
        __syncthreads();

        // ---- conv2 partial sum over these 16 input channels ----
        // lane -> spatial (sy,sx); wave -> 16 output channels.
        // cw2 accessed from wave-uniform base with compile-time offsets in
        // contiguous 36-float runs per (o, icpb) -> s_load_dwordx16 batches.
        const float* wb2 = cw2 + wid * 9216 + chunk * 144;
        const int lbase = 40 * sy + sx;
        for (int icpb = 0; icpb < 4; ++icpb) {       // keep rolled: bounds live SGPRs
            float cv[4][9];
            #pragma unroll
            for (int icp4 = 0; icp4 < 4; ++icp4)
            #pragma unroll
            for (int kh = 0; kh < 3; ++kh)
            #pragma unroll
            for (int kw = 0; kw < 3; ++kw)
                cv[icp4][kh * 3 + kw] = c1s[(icpb * 4 + icp4) * 340 + lbase
                                            + 20 * kh + (kw & 1) * 10 + (kw >> 1)];
            #pragma unroll
            for (int o = 0; o < 16; ++o) {
                float a = acc2[o];
                #pragma unroll
                for (int icp4 = 0; icp4 < 4; ++icp4)
                #pragma unroll
                for (int k9 = 0; k9 < 9; ++k9)
                    a = fmaf(cv[icp4][k9], wb2[o * 576 + icpb * 36 + icp4 * 9 + k9], a);
                acc2[o] = a;
            }
        }
        __syncthreads();   // before next chunk overwrites c1s
    }

    // ---- relu then mean over the 64 spatial lanes, per channel ----
    #pragma unroll
    for (int o = 0; o < 16; ++o) {
        float v = fmaxf(acc2[o], 0.f);
        v += __shfl_xor(v, 32, 64);
        v += __shfl_xor(v, 16, 64);
        v += __shfl_xor(v,  8, 64);
        v += __shfl_xor(v,  4, 64);
        v += __shfl_xor(v,  2, 64);
        v += __shfl_xor(v,  1, 64);
        if (lane == o) tok[wid * 16 + o] = v * (1.f / 64.f);
    }
    __syncthreads();

    // ---- attention MLP 64->32->1, sigmoid, threshold ----
    if (tid < 32) {
        float u = ab1[tid];
        #pragma unroll 8
        for (int k = 0; k < 64; ++k) u = fmaf(aw1[tid * 64 + k], tok[k], u);
        ured[tid] = fmaxf(u, 0.f);
    }
    __syncthreads();
    if (tid == 0) {
        float x = ab2[0];
        #pragma unroll 8
        for (int j = 0; j < 32; ++j) x = fmaf(aw2[j], ured[j], x);
        const float score = 1.f / (1.f + expf(-x));
        mask_out[blk] = (score > thr[0]) ? 1.f : 0.f;   // forward value of ST mask
    }
}

// ---------------------------------------------------------------------------
// Tiled f32 GEMM: C = act(A(MxK) * W(NxK)^T + bias) [* mask | * (1-mask)] [+= C]
// 256 threads as 16x16; thread computes TM x TN. BK=16. All K here are %16==0,
// all M are %BM==0; only N needs guarding (N=10 head).
// Launch configs below keep grid >= 512 blocks for the big layers (2 blk/CU).
// ---------------------------------------------------------------------------
template<int BM, int BN, int TM, int TN, bool RELU, int MMODE, bool ACCUM>
__global__ __launch_bounds__(256, 2)
void gemm_kernel(const float* __restrict__ A, const float* __restrict__ W,
                 const float* __restrict__ bias, const float* __restrict__ mask,
                 float* __restrict__ C, int M, int N, int K)
{
    constexpr int BK  = 16;
    constexpr int LDA = BM + 4;   // rows stay 16B-aligned
    constexpr int LDB = BN + 4;
    __shared__ float As[BK][LDA];
    __shared__ float Ws[BK][LDB];

    const int tid = threadIdx.x;
    const int tx = tid & 15;      // n
    const int ty = tid >> 4;      // m
    const int bm = blockIdx.x * BM;
    const int bn = blockIdx.y * BN;

    float acc[TM][TN];
    #pragma unroll
    for (int i = 0; i < TM; ++i)
        #pragma unroll
        for (int j = 0; j < TN; ++j) acc[i][j] = 0.f;

    constexpr int ACH = (BM * BK) / (4 * 256);  // float4 chunks/thread (A)
    constexpr int BCH = (BN * BK) / (4 * 256);  // float4 chunks/thread (W)

    for (int k0 = 0; k0 < K; k0 += BK) {
        #pragma unroll
        for (int q = 0; q < ACH; ++q) {
            const int c = tid + q * 256;
            const int m = c >> 2;
            const int kq = (c & 3) * 4;
            const float4 v = *(const float4*)&A[(size_t)(bm + m) * K + k0 + kq];
            As[kq + 0][m] = v.x; As[kq + 1][m] = v.y;
            As[kq + 2][m] = v.z; As[kq + 3][m] = v.w;
        }
        #pragma unroll
        for (int q = 0; q < BCH; ++q) {
            const int c = tid + q * 256;
            const int n = c >> 2;
            const int kq = (c & 3) * 4;
            float4 v = make_float4(0.f, 0.f, 0.f, 0.f);
            if (bn + n < N) v = *(const float4*)&W[(size_t)(bn + n) * K + k0 + kq];
            Ws[kq + 0][n] = v.x; Ws[kq + 1][n] = v.y;
            Ws[kq + 2][n] = v.z; Ws[kq + 3][n] = v.w;
        }
        __syncthreads();

        #pragma unroll
        for (int k = 0; k < BK; ++k) {
            float av[TM], bv[TN];
            {
                const float4 t0 = *(const float4*)&As[k][ty * TM];
                av[0] = t0.x; av[1] = t0.y; av[2] = t0.z; av[3] = t0.w;
                if constexpr (TM == 8) {
                    const float4 t1 = *(const float4*)&As[k][ty * TM + 4];
                    av[4] = t1.x; av[5] = t1.y; av[6] = t1.z; av[7] = t1.w;
                }
            }
            {
                const float4 t0 = *(const float4*)&Ws[k][tx * TN];
                bv[0] = t0.x; bv[1] = t0.y; bv[2] = t0.z; bv[3] = t0.w;
                if constexpr (TN == 8) {
                    const float4 t1 = *(const float4*)&Ws[k][tx * TN + 4];
                    bv[4] = t1.x; bv[5] = t1.y; bv[6] = t1.z; bv[7] = t1.w;
                }
            }
            #pragma unroll
            for (int i = 0; i < TM; ++i)
                #pragma unroll
                for (int j = 0; j < TN; ++j)
                    acc[i][j] = fmaf(av[i], bv[j], acc[i][j]);
        }
        __syncthreads();
    }

    #pragma unroll
    for (int i = 0; i < TM; ++i) {
        const int row = bm + ty * TM + i;
        float mv = 1.f;
        if (MMODE == 1) mv = mask[row];
        if (MMODE == 2) mv = 1.f - mask[row];
        #pragma unroll
        for (int j = 0; j < TN; ++j) {
            const int col = bn + tx * TN + j;
            if (col < N) {
                float v = acc[i][j] + bias[col];
                if (RELU)  v = fmaxf(v, 0.f);
                if (MMODE) v *= mv;
                const size_t o = (size_t)row * N + col;
                C[o] = ACCUM ? (C[o] + v) : v;
            }
        }
    }
}

// ---------------------------------------------------------------------------
extern "C" void kernel_launch(void* const* d_in, const int* in_sizes, int n_in,
                              void* d_out, int out_size, void* d_ws, size_t ws_size,
                              hipStream_t stream)
{
    (void)in_sizes; (void)n_in; (void)out_size; (void)ws_size;
    const float* images = (const float*)d_in[0];
    const float* patches= (const float*)d_in[1];
    const float* cw1 = (const float*)d_in[2];
    const float* cb1 = (const float*)d_in[3];
    const float* cw2 = (const float*)d_in[4];
    const float* cb2 = (const float*)d_in[5];
    const float* aw1 = (const float*)d_in[6];
    const float* ab1 = (const float*)d_in[7];
    const float* aw2 = (const float*)d_in[8];
    const float* ab2 = (const float*)d_in[9];
    const float* thr = (const float*)d_in[10];
    const float* bw1 = (const float*)d_in[11];
    const float* bb1 = (const float*)d_in[12];
    const float* bw2 = (const float*)d_in[13];
    const float* bb2 = (const float*)d_in[14];
    const float* bw3 = (const float*)d_in[15];
    const float* bb3 = (const float*)d_in[16];
    const float* bwo = (const float*)d_in[17];
    const float* bbo = (const float*)d_in[18];
    const float* sw1 = (const float*)d_in[19];
    const float* sb1 = (const float*)d_in[20];
    const float* swo = (const float*)d_in[21];
    const float* sbo = (const float*)d_in[22];
    const float* gw  = (const float*)d_in[23];
    const float* gb  = (const float*)d_in[24];
    const float* hw1 = (const float*)d_in[25];
    const float* hb1 = (const float*)d_in[26];
    const float* hw2 = (const float*)d_in[27];
    const float* hb2 = (const float*)d_in[28];
    float* out = (float*)d_out;
    float* ws  = (float*)d_ws;

    // workspace layout (floats): total ~36.8 MB
    float* mask = ws;                      // 8192
    float* HA   = ws + 8192;               // 8192*512
    float* HB   = HA + 8192 * 512;         // 8192*512
    float* CMB  = HB + 8192 * 512;         // 8192*128
    float* G    = CMB + 8192 * 128;        // 512*256
    float* T    = G + 512 * 256;           // 512*128

    // router mask (exact f32 score chain)
    conv_attn_kernel<<<8192, 256, 0, stream>>>(images, cw1, cb1, cw2, cb2,
                                               aw1, ab1, aw2, ab2, thr, mask);

    // big MLP: pf -> 512 -> 512 -> 512 -> 128 (masked)  [grid >= 512 blocks]
    gemm_kernel<128,64,8,4,true ,0,false><<<dim3(64,8), 256, 0, stream>>>(patches, bw1, bb1, nullptr, HA, 8192, 512, 3072);
    gemm_kernel<128,64,8,4,true ,0,false><<<dim3(64,8), 256, 0, stream>>>(HA,      bw2, bb2, nullptr, HB, 8192, 512, 512);
    gemm_kernel<128,64,8,4,true ,0,false><<<dim3(64,8), 256, 0, stream>>>(HB,      bw3, bb3, nullptr, HA, 8192, 512, 512);
    gemm_kernel<128,64,8,4,false,1,false><<<dim3(64,2), 256, 0, stream>>>(HA,      bwo, bbo, mask,    CMB, 8192, 128, 512);

    // small MLP: pf -> 64 -> 128 ((1-mask), accumulated into CMB)
    gemm_kernel<64,64,4,4,true ,0,false><<<dim3(128,1), 256, 0, stream>>>(patches, sw1, sb1, nullptr, HB, 8192, 64, 3072);
    gemm_kernel<128,64,8,4,false,2,true ><<<dim3(64,2), 256, 0, stream>>>(HB,      swo, sbo, mask,    CMB, 8192, 128, 64);

    // aggregator (B,2048)->256, head 256->128->10
    gemm_kernel<64,64,4,4,false,0,false><<<dim3(8,4), 256, 0, stream>>>(CMB, gw,  gb,  nullptr, G,   512, 256, 2048);
    gemm_kernel<64,64,4,4,true ,0,false><<<dim3(8,2), 256, 0, stream>>>(G,   hw1, hb1, nullptr, T,   512, 128, 256);
    gemm_kernel<64,64,4,4,false,0,false><<<dim3(8,1), 256, 0, stream>>>(T,   hw2, hb2, nullptr, out, 512, 10,  128);
}

// Round 11
// 1564.144 us; speedup vs baseline: 2.0866x; 1.2993x over previous
//
#include <hip/hip_runtime.h>
#include <math.h>

typedef float f32x4 __attribute__((ext_vector_type(4)));
typedef short s16x8 __attribute__((ext_vector_type(8)));

static __device__ __forceinline__ unsigned short f2bf(float f) {
    unsigned u = __float_as_uint(f);
    u += 0x7FFF + ((u >> 16) & 1);          // RNE f32 -> bf16
    return (unsigned short)(u >> 16);
}

// ---------------------------------------------------------------------------
// Fused conv1(3->64,3x3,s2) + relu + conv2(64->64,3x3,s2) + relu + 8x8 pool
//       + attention MLP + threshold  ->  mask[B*16]   (exact f32 chain)
// 8-oc chunks: LDS 26.4 KB -> 6 blocks/CU (hide SMEM weight-stream latency).
// ---------------------------------------------------------------------------
__global__ __launch_bounds__(256, 6)
void conv_attn_kernel(const float* __restrict__ images,
                      const float* __restrict__ cw1, const float* __restrict__ cb1,
                      const float* __restrict__ cw2, const float* __restrict__ cb2,
                      const float* __restrict__ aw1, const float* __restrict__ ab1,
                      const float* __restrict__ aw2, const float* __restrict__ ab2,
                      const float* __restrict__ thr, float* __restrict__ mask_out)
{
    __shared__ float in_s[3 * 35 * 36];          // 15120 B, parity-split x
    __shared__ float c1s[8 * 17 * 20];           // 10880 B, parity-split x
    __shared__ float tok[64];
    __shared__ float ured[32];

    const int blk   = blockIdx.x;
    const int b     = blk >> 4;
    const int patch = blk & 15;
    const int pr = patch >> 2, pc = patch & 3;
    const int tid = threadIdx.x;
    const float* img = images + (size_t)b * (3 * 128 * 128);

    const int wid  = __builtin_amdgcn_readfirstlane(tid >> 6);
    const int lane = tid & 63;
    const int sy = lane >> 3, sx = lane & 7;

    // stage input tile (rows 32pr..+34, cols 32pc..+34), OOB=0
    for (int idx = tid; idx < 3 * 35 * 35; idx += 256) {
        const int c   = idx / 1225;
        const int rem = idx - c * 1225;
        const int y   = rem / 35;
        const int x   = rem - y * 35;
        const int gy  = 32 * pr + y, gx = 32 * pc + x;
        float v = 0.f;
        if (gy < 128 && gx < 128) v = img[c * 16384 + gy * 128 + gx];
        in_s[c * 1260 + y * 36 + (x & 1) * 18 + (x >> 1)] = v;
    }
    __syncthreads();

    float acc2[16];
    #pragma unroll
    for (int o = 0; o < 16; ++o) acc2[o] = cb2[wid * 16 + o];

    for (int chunk = 0; chunk < 8; ++chunk) {
        const float* wb1  = cw1 + chunk * 8 * 27;
        const float* cb1c = cb1 + chunk * 8;

        // conv1 + relu for oc in [8*chunk, 8*chunk+8)
        for (int p = tid; p < 289; p += 256) {
            const int ty = p / 17, tx = p % 17;
            const int oy = 16 * pr + ty, ox = 16 * pc + tx;
            float vals[8];
            if (oy < 64 && ox < 64) {
                float iv[27];
                #pragma unroll
                for (int ic = 0; ic < 3; ++ic)
                #pragma unroll
                for (int kh = 0; kh < 3; ++kh)
                #pragma unroll
                for (int kw = 0; kw < 3; ++kw)
                    iv[(ic * 3 + kh) * 3 + kw] =
                        in_s[ic * 1260 + (2 * ty + kh) * 36 + (kw & 1) * 18 + tx + (kw >> 1)];
                #pragma unroll
                for (int o = 0; o < 8; ++o) {
                    float a = cb1c[o];
                    #pragma unroll
                    for (int k = 0; k < 27; ++k) a = fmaf(iv[k], wb1[o * 27 + k], a);
                    vals[o] = fmaxf(a, 0.f);
                }
            } else {
                #pragma unroll
                for (int o = 0; o < 8; ++o) vals[o] = 0.f;
            }
            const int base = ty * 20 + (tx & 1) * 10 + (tx >> 1);
            #pragma unroll
            for (int o = 0; o < 8; ++o) c1s[o * 340 + base] = vals[o];
        }
        __syncthreads();

        // conv2 partial sums over these 8 input channels
        const float* wb2 = cw2 + wid * 9216 + chunk * 72;
        const int lbase = 40 * sy + sx;
        for (int icpb = 0; icpb < 2; ++icpb) {
            float cv[4][9];
            #pragma unroll
            for (int icp4 = 0; icp4 < 4; ++icp4)
            #pragma unroll
            for (int kh = 0; kh < 3; ++kh)
            #pragma unroll
            for (int kw = 0; kw < 3; ++kw)
                cv[icp4][kh * 3 + kw] = c1s[(icpb * 4 + icp4) * 340 + lbase
                                            + 20 * kh + (kw & 1) * 10 + (kw >> 1)];
            #pragma unroll
            for (int o = 0; o < 16; ++o) {
                float a = acc2[o];
                #pragma unroll
                for (int icp4 = 0; icp4 < 4; ++icp4)
                #pragma unroll
                for (int k9 = 0; k9 < 9; ++k9)
                    a = fmaf(cv[icp4][k9], wb2[o * 576 + (icpb * 4 + icp4) * 9 + k9], a);
                acc2[o] = a;
            }
        }
        __syncthreads();
    }

    // relu + mean over 64 spatial lanes, per channel
    #pragma unroll
    for (int o = 0; o < 16; ++o) {
        float v = fmaxf(acc2[o], 0.f);
        v += __shfl_xor(v, 32, 64);
        v += __shfl_xor(v, 16, 64);
        v += __shfl_xor(v,  8, 64);
        v += __shfl_xor(v,  4, 64);
        v += __shfl_xor(v,  2, 64);
        v += __shfl_xor(v,  1, 64);
        if (lane == o) tok[wid * 16 + o] = v * (1.f / 64.f);
    }
    __syncthreads();

    // attention MLP 64->32->1, sigmoid, threshold
    if (tid < 32) {
        float u = ab1[tid];
        #pragma unroll 8
        for (int k = 0; k < 64; ++k) u = fmaf(aw1[tid * 64 + k], tok[k], u);
        ured[tid] = fmaxf(u, 0.f);
    }
    __syncthreads();
    if (tid == 0) {
        float x = ab2[0];
        #pragma unroll 8
        for (int j = 0; j < 32; ++j) x = fmaf(aw2[j], ured[j], x);
        const float score = 1.f / (1.f + expf(-x));
        mask_out[blk] = (score > thr[0]) ? 1.f : 0.f;
    }
}

// ---------------------------------------------------------------------------
// bf16 MFMA GEMM: C = act(A(MxK) @ W(NxK)^T + bias) [*mask|*(1-mask)] [+=C]
// 16x16x32 bf16 MFMA, f32 accum. BN=64 fixed, BM in {32,64,128}; 4 waves as
// 2x2; wave tile (BM/2)x32 -> FM x 2 fragments. A staged f32->bf16 (RNE) or
// bf16 passthrough; W staged f32->bf16. LDS rows padded to 40 bf16 (80 B,
// 16B-aligned, 2-way banks = free). C/D layout: col=lane&15,
// row=(lane>>4)*4+reg [m89-verified]; A/B share one k-slot mapping so any
// k permutation cancels between operands.
// ---------------------------------------------------------------------------
template<int BM, bool A_BF16, bool RELU, int MMODE, bool OUT_BF16, bool ACCUM>
__global__ __launch_bounds__(256, 2)
void mfma_gemm(const void* __restrict__ Av, const float* __restrict__ W,
               const float* __restrict__ bias, const float* __restrict__ mask,
               void* __restrict__ Cv, int M, int N, int K)
{
    constexpr int LD = 40;             // bf16 elems per LDS row
    constexpr int FM = BM / 32;
    __shared__ unsigned short As[BM][LD];
    __shared__ unsigned short Bs[64][LD];

    const int tid  = threadIdx.x;
    const int lane = tid & 63;
    const int l15  = lane & 15;
    const int kg   = lane >> 4;
    const int w    = tid >> 6;
    const int wm   = w >> 1;
    const int wn   = w & 1;
    const int bm   = blockIdx.x * BM;
    const int bn   = blockIdx.y * 64;
    (void)M;

    f32x4 acc[FM][2];
    #pragma unroll
    for (int i = 0; i < FM; ++i)
        #pragma unroll
        for (int j = 0; j < 2; ++j) acc[i][j] = (f32x4){0.f, 0.f, 0.f, 0.f};

    for (int k0 = 0; k0 < K; k0 += 32) {
        // ---- stage A tile (BM x 32) ----
        #pragma unroll
        for (int q = 0; q < BM / 32; ++q) {
            const int c   = tid + q * 256;
            const int row = c >> 3;
            const int kq  = (c & 7) * 4;
            if (A_BF16) {
                const unsigned short* A = (const unsigned short*)Av;
                uint2 v = *(const uint2*)(A + (size_t)(bm + row) * K + k0 + kq);
                *(uint2*)&As[row][kq] = v;
            } else {
                const float* A = (const float*)Av;
                const float4 v = *(const float4*)(A + (size_t)(bm + row) * K + k0 + kq);
                uint2 pk;
                pk.x = (unsigned)f2bf(v.x) | ((unsigned)f2bf(v.y) << 16);
                pk.y = (unsigned)f2bf(v.z) | ((unsigned)f2bf(v.w) << 16);
                *(uint2*)&As[row][kq] = pk;
            }
        }
        // ---- stage B tile (64 x 32) from W (f32, [N][K]) ----
        #pragma unroll
        for (int q = 0; q < 2; ++q) {
            const int c   = tid + q * 256;
            const int row = c >> 3;
            const int kq  = (c & 7) * 4;
            const float4 v = *(const float4*)(W + (size_t)(bn + row) * K + k0 + kq);
            uint2 pk;
            pk.x = (unsigned)f2bf(v.x) | ((unsigned)f2bf(v.y) << 16);
            pk.y = (unsigned)f2bf(v.z) | ((unsigned)f2bf(v.w) << 16);
            *(uint2*)&Bs[row][kq] = pk;
        }
        __syncthreads();

        s16x8 a[FM], bfr[2];
        #pragma unroll
        for (int fm = 0; fm < FM; ++fm)
            a[fm] = *(const s16x8*)&As[wm * (BM / 2) + fm * 16 + l15][kg * 8];
        #pragma unroll
        for (int fn = 0; fn < 2; ++fn)
            bfr[fn] = *(const s16x8*)&Bs[wn * 32 + fn * 16 + l15][kg * 8];

        #pragma unroll
        for (int fm = 0; fm < FM; ++fm)
            #pragma unroll
            for (int fn = 0; fn < 2; ++fn)
                acc[fm][fn] = __builtin_amdgcn_mfma_f32_16x16x32_bf16(
                                  a[fm], bfr[fn], acc[fm][fn], 0, 0, 0);
        __syncthreads();
    }

    // ---- epilogue ----
    #pragma unroll
    for (int fm = 0; fm < FM; ++fm) {
        #pragma unroll
        for (int fn = 0; fn < 2; ++fn) {
            const int col = bn + wn * 32 + fn * 16 + l15;
            #pragma unroll
            for (int r = 0; r < 4; ++r) {
                const int row = bm + wm * (BM / 2) + fm * 16 + kg * 4 + r;
                float v = acc[fm][fn][r] + bias[col];
                if (RELU) v = fmaxf(v, 0.f);
                if (MMODE == 1) v *= mask[row];
                if (MMODE == 2) v *= (1.f - mask[row]);
                const size_t o = (size_t)row * N + col;
                if (OUT_BF16) {
                    ((unsigned short*)Cv)[o] = f2bf(v);
                } else {
                    float* C = (float*)Cv;
                    C[o] = ACCUM ? (C[o] + v) : v;
                }
            }
        }
    }
}

// ---------------------------------------------------------------------------
// f32 VALU GEMM (kept for aggregator + head): C = act(A @ W^T + b)
// ---------------------------------------------------------------------------
template<int BM, int BN, int TM, int TN, bool RELU>
__global__ __launch_bounds__(256, 2)
void gemm_kernel(const float* __restrict__ A, const float* __restrict__ W,
                 const float* __restrict__ bias, float* __restrict__ C,
                 int M, int N, int K)
{
    constexpr int BK  = 16;
    constexpr int LDA = BM + 4;
    constexpr int LDB = BN + 4;
    __shared__ float As[BK][LDA];
    __shared__ float Ws[BK][LDB];

    const int tid = threadIdx.x;
    const int tx = tid & 15;
    const int ty = tid >> 4;
    const int bm = blockIdx.x * BM;
    const int bn = blockIdx.y * BN;

    float acc[TM][TN];
    #pragma unroll
    for (int i = 0; i < TM; ++i)
        #pragma unroll
        for (int j = 0; j < TN; ++j) acc[i][j] = 0.f;

    constexpr int ACH = (BM * BK) / (4 * 256);
    constexpr int BCH = (BN * BK) / (4 * 256);

    for (int k0 = 0; k0 < K; k0 += BK) {
        #pragma unroll
        for (int q = 0; q < ACH; ++q) {
            const int c = tid + q * 256;
            const int m = c >> 2;
            const int kq = (c & 3) * 4;
            const float4 v = *(const float4*)&A[(size_t)(bm + m) * K + k0 + kq];
            As[kq + 0][m] = v.x; As[kq + 1][m] = v.y;
            As[kq + 2][m] = v.z; As[kq + 3][m] = v.w;
        }
        #pragma unroll
        for (int q = 0; q < BCH; ++q) {
            const int c = tid + q * 256;
            const int n = c >> 2;
            const int kq = (c & 3) * 4;
            float4 v = make_float4(0.f, 0.f, 0.f, 0.f);
            if (bn + n < N) v = *(const float4*)&W[(size_t)(bn + n) * K + k0 + kq];
            Ws[kq + 0][n] = v.x; Ws[kq + 1][n] = v.y;
            Ws[kq + 2][n] = v.z; Ws[kq + 3][n] = v.w;
        }
        __syncthreads();

        #pragma unroll
        for (int k = 0; k < BK; ++k) {
            float av[TM], bv[TN];
            {
                const float4 t0 = *(const float4*)&As[k][ty * TM];
                av[0] = t0.x; av[1] = t0.y; av[2] = t0.z; av[3] = t0.w;
            }
            {
                const float4 t0 = *(const float4*)&Ws[k][tx * TN];
                bv[0] = t0.x; bv[1] = t0.y; bv[2] = t0.z; bv[3] = t0.w;
            }
            #pragma unroll
            for (int i = 0; i < TM; ++i)
                #pragma unroll
                for (int j = 0; j < TN; ++j)
                    acc[i][j] = fmaf(av[i], bv[j], acc[i][j]);
        }
        __syncthreads();
    }

    #pragma unroll
    for (int i = 0; i < TM; ++i) {
        const int row = bm + ty * TM + i;
        #pragma unroll
        for (int j = 0; j < TN; ++j) {
            const int col = bn + tx * TN + j;
            if (col < N) {
                float v = acc[i][j] + bias[col];
                if (RELU) v = fmaxf(v, 0.f);
                C[(size_t)row * N + col] = v;
            }
        }
    }
}

// ---------------------------------------------------------------------------
extern "C" void kernel_launch(void* const* d_in, const int* in_sizes, int n_in,
                              void* d_out, int out_size, void* d_ws, size_t ws_size,
                              hipStream_t stream)
{
    (void)in_sizes; (void)n_in; (void)out_size; (void)ws_size;
    const float* images = (const float*)d_in[0];
    const float* patches= (const float*)d_in[1];
    const float* cw1 = (const float*)d_in[2];
    const float* cb1 = (const float*)d_in[3];
    const float* cw2 = (const float*)d_in[4];
    const float* cb2 = (const float*)d_in[5];
    const float* aw1 = (const float*)d_in[6];
    const float* ab1 = (const float*)d_in[7];
    const float* aw2 = (const float*)d_in[8];
    const float* ab2 = (const float*)d_in[9];
    const float* thr = (const float*)d_in[10];
    const float* bw1 = (const float*)d_in[11];
    const float* bb1 = (const float*)d_in[12];
    const float* bw2 = (const float*)d_in[13];
    const float* bb2 = (const float*)d_in[14];
    const float* bw3 = (const float*)d_in[15];
    const float* bb3 = (const float*)d_in[16];
    const float* bwo = (const float*)d_in[17];
    const float* bbo = (const float*)d_in[18];
    const float* sw1 = (const float*)d_in[19];
    const float* sb1 = (const float*)d_in[20];
    const float* swo = (const float*)d_in[21];
    const float* sbo = (const float*)d_in[22];
    const float* gw  = (const float*)d_in[23];
    const float* gb  = (const float*)d_in[24];
    const float* hw1 = (const float*)d_in[25];
    const float* hb1 = (const float*)d_in[26];
    const float* hw2 = (const float*)d_in[27];
    const float* hb2 = (const float*)d_in[28];
    float* out = (float*)d_out;
    float* ws  = (float*)d_ws;

    // workspace layout: ~21.5 MB
    float* mask = ws;                                        // 8192 f32
    float* CMB  = ws + 8192;                                 // 8192*128 f32
    float* G    = CMB + 8192 * 128;                          // 512*256 f32
    float* T    = G + 512 * 256;                             // 512*128 f32
    unsigned short* X1  = (unsigned short*)(T + 512 * 128);  // 8192*512 bf16
    unsigned short* X2  = X1 + 8192 * 512;                   // 8192*512 bf16
    unsigned short* S16 = X2 + 8192 * 512;                   // 8192*64  bf16

    // router mask (exact f32 score chain)
    conv_attn_kernel<<<8192, 256, 0, stream>>>(images, cw1, cb1, cw2, cb2,
                                               aw1, ab1, aw2, ab2, thr, mask);

    // big MLP (bf16 MFMA): pf -> 512 -> 512 -> 512 -> 128 (masked)
    mfma_gemm<128,false,true ,0,true ,false><<<dim3(64,8), 256, 0, stream>>>(patches, bw1, bb1, nullptr, X1, 8192, 512, 3072);
    mfma_gemm<128,true ,true ,0,true ,false><<<dim3(64,8), 256, 0, stream>>>(X1,      bw2, bb2, nullptr, X2, 8192, 512, 512);
    mfma_gemm<128,true ,true ,0,true ,false><<<dim3(64,8), 256, 0, stream>>>(X2,      bw3, bb3, nullptr, X1, 8192, 512, 512);
    mfma_gemm<64 ,true ,false,1,false,false><<<dim3(128,2),256, 0, stream>>>(X1,      bwo, bbo, mask,    CMB, 8192, 128, 512);

    // small MLP (bf16 MFMA): pf -> 64 -> 128, (1-mask) accumulated into CMB
    mfma_gemm<32 ,false,true ,0,true ,false><<<dim3(256,1),256, 0, stream>>>(patches, sw1, sb1, nullptr, S16, 8192, 64, 3072);
    mfma_gemm<64 ,true ,false,2,false,true ><<<dim3(128,2),256, 0, stream>>>(S16,     swo, sbo, mask,    CMB, 8192, 128, 64);

    // aggregator (512,2048)->256 + head 256->128->10 (f32 tail)
    gemm_kernel<64,64,4,4,false><<<dim3(8,4), 256, 0, stream>>>(CMB, gw,  gb,  G,   512, 256, 2048);
    gemm_kernel<64,64,4,4,true ><<<dim3(8,2), 256, 0, stream>>>(G,   hw1, hb1, T,   512, 128, 256);
    gemm_kernel<64,64,4,4,false><<<dim3(8,1), 256, 0, stream>>>(T,   hw2, hb2, out, 512, 10,  128);
}

// Round 12
// 1235.336 us; speedup vs baseline: 2.6420x; 1.2662x over previous
//
#include <hip/hip_runtime.h>
#include <math.h>

typedef float f32x4 __attribute__((ext_vector_type(4)));
typedef short s16x8 __attribute__((ext_vector_type(8)));

static __device__ __forceinline__ unsigned short f2bf(float f) {
    unsigned u = __float_as_uint(f);
    u += 0x7FFF + ((u >> 16) & 1);          // RNE f32 -> bf16
    return (unsigned short)(u >> 16);
}

// ---------------------------------------------------------------------------
// Multi-segment f32 -> bf16 converter (weights pre-pass, one launch).
// blockIdx.y selects the segment; grid-stride in x; 8 elems/thread.
// ---------------------------------------------------------------------------
struct CvtSeg { const float* s; unsigned short* d; int n; };
struct CvtArgs { CvtSeg seg[7]; };

__global__ __launch_bounds__(256)
void cvt_kernel(CvtArgs a)
{
    const CvtSeg sg = a.seg[blockIdx.y];
    const int stride = gridDim.x * 256 * 8;
    for (int i = (blockIdx.x * 256 + threadIdx.x) * 8; i < sg.n; i += stride) {
        const float4 v0 = *(const float4*)(sg.s + i);
        const float4 v1 = *(const float4*)(sg.s + i + 4);
        uint4 pk;
        pk.x = (unsigned)f2bf(v0.x) | ((unsigned)f2bf(v0.y) << 16);
        pk.y = (unsigned)f2bf(v0.z) | ((unsigned)f2bf(v0.w) << 16);
        pk.z = (unsigned)f2bf(v1.x) | ((unsigned)f2bf(v1.y) << 16);
        pk.w = (unsigned)f2bf(v1.z) | ((unsigned)f2bf(v1.w) << 16);
        *(uint4*)(sg.d + i) = pk;
    }
}

// ---------------------------------------------------------------------------
// Fused conv1(3->64,3x3,s2) + relu + conv2(64->64,3x3,s2) + relu + 8x8 pool
//       + attention MLP + threshold  ->  mask[B*16]   (exact f32 chain)
// UNCHANGED from round 11 (measured 861 us, Occ 65%, VALUBusy 57%).
// ---------------------------------------------------------------------------
__global__ __launch_bounds__(256, 6)
void conv_attn_kernel(const float* __restrict__ images,
                      const float* __restrict__ cw1, const float* __restrict__ cb1,
                      const float* __restrict__ cw2, const float* __restrict__ cb2,
                      const float* __restrict__ aw1, const float* __restrict__ ab1,
                      const float* __restrict__ aw2, const float* __restrict__ ab2,
                      const float* __restrict__ thr, float* __restrict__ mask_out)
{
    __shared__ float in_s[3 * 35 * 36];          // 15120 B, parity-split x
    __shared__ float c1s[8 * 17 * 20];           // 10880 B, parity-split x
    __shared__ float tok[64];
    __shared__ float ured[32];

    const int blk   = blockIdx.x;
    const int b     = blk >> 4;
    const int patch = blk & 15;
    const int pr = patch >> 2, pc = patch & 3;
    const int tid = threadIdx.x;
    const float* img = images + (size_t)b * (3 * 128 * 128);

    const int wid  = __builtin_amdgcn_readfirstlane(tid >> 6);
    const int lane = tid & 63;
    const int sy = lane >> 3, sx = lane & 7;

    for (int idx = tid; idx < 3 * 35 * 35; idx += 256) {
        const int c   = idx / 1225;
        const int rem = idx - c * 1225;
        const int y   = rem / 35;
        const int x   = rem - y * 35;
        const int gy  = 32 * pr + y, gx = 32 * pc + x;
        float v = 0.f;
        if (gy < 128 && gx < 128) v = img[c * 16384 + gy * 128 + gx];
        in_s[c * 1260 + y * 36 + (x & 1) * 18 + (x >> 1)] = v;
    }
    __syncthreads();

    float acc2[16];
    #pragma unroll
    for (int o = 0; o < 16; ++o) acc2[o] = cb2[wid * 16 + o];

    for (int chunk = 0; chunk < 8; ++chunk) {
        const float* wb1  = cw1 + chunk * 8 * 27;
        const float* cb1c = cb1 + chunk * 8;

        for (int p = tid; p < 289; p += 256) {
            const int ty = p / 17, tx = p % 17;
            const int oy = 16 * pr + ty, ox = 16 * pc + tx;
            float vals[8];
            if (oy < 64 && ox < 64) {
                float iv[27];
                #pragma unroll
                for (int ic = 0; ic < 3; ++ic)
                #pragma unroll
                for (int kh = 0; kh < 3; ++kh)
                #pragma unroll
                for (int kw = 0; kw < 3; ++kw)
                    iv[(ic * 3 + kh) * 3 + kw] =
                        in_s[ic * 1260 + (2 * ty + kh) * 36 + (kw & 1) * 18 + tx + (kw >> 1)];
                #pragma unroll
                for (int o = 0; o < 8; ++o) {
                    float a = cb1c[o];
                    #pragma unroll
                    for (int k = 0; k < 27; ++k) a = fmaf(iv[k], wb1[o * 27 + k], a);
                    vals[o] = fmaxf(a, 0.f);
                }
            } else {
                #pragma unroll
                for (int o = 0; o < 8; ++o) vals[o] = 0.f;
            }
            const int base = ty * 20 + (tx & 1) * 10 + (tx >> 1);
            #pragma unroll
            for (int o = 0; o < 8; ++o) c1s[o * 340 + base] = vals[o];
        }
        __syncthreads();

        const float* wb2 = cw2 + wid * 9216 + chunk * 72;
        const int lbase = 40 * sy + sx;
        for (int icpb = 0; icpb < 2; ++icpb) {
            float cv[4][9];
            #pragma unroll
            for (int icp4 = 0; icp4 < 4; ++icp4)
            #pragma unroll
            for (int kh = 0; kh < 3; ++kh)
            #pragma unroll
            for (int kw = 0; kw < 3; ++kw)
                cv[icp4][kh * 3 + kw] = c1s[(icpb * 4 + icp4) * 340 + lbase
                                            + 20 * kh + (kw & 1) * 10 + (kw >> 1)];
            #pragma unroll
            for (int o = 0; o < 16; ++o) {
                float a = acc2[o];
                #pragma unroll
                for (int icp4 = 0; icp4 < 4; ++icp4)
                #pragma unroll
                for (int k9 = 0; k9 < 9; ++k9)
                    a = fmaf(cv[icp4][k9], wb2[o * 576 + (icpb * 4 + icp4) * 9 + k9], a);
                acc2[o] = a;
            }
        }
        __syncthreads();
    }

    #pragma unroll
    for (int o = 0; o < 16; ++o) {
        float v = fmaxf(acc2[o], 0.f);
        v += __shfl_xor(v, 32, 64);
        v += __shfl_xor(v, 16, 64);
        v += __shfl_xor(v,  8, 64);
        v += __shfl_xor(v,  4, 64);
        v += __shfl_xor(v,  2, 64);
        v += __shfl_xor(v,  1, 64);
        if (lane == o) tok[wid * 16 + o] = v * (1.f / 64.f);
    }
    __syncthreads();

    if (tid < 32) {
        float u = ab1[tid];
        #pragma unroll 8
        for (int k = 0; k < 64; ++k) u = fmaf(aw1[tid * 64 + k], tok[k], u);
        ured[tid] = fmaxf(u, 0.f);
    }
    __syncthreads();
    if (tid == 0) {
        float x = ab2[0];
        #pragma unroll 8
        for (int j = 0; j < 32; ++j) x = fmaf(aw2[j], ured[j], x);
        const float score = 1.f / (1.f + expf(-x));
        mask_out[blk] = (score > thr[0]) ? 1.f : 0.f;
    }
}

// ---------------------------------------------------------------------------
// bf16 MFMA GEMM v2: C = act(A(MxK) @ W16(NxK)^T + bias) [*mask|*(1-m)] [+aux]
// BK=64, BN=64, BM in {32,64}; 4 waves 2x2 (wave tile (BM/2)x32).
// W is PRE-CONVERTED bf16 -> staging is pure 16B copies. A either bf16
// (intermediates) or f32 (patches, converted in-loop). 4 blocks/CU.
// LDS rows 72 bf16 = 144 B (16B-aligned). C/D layout col=lane&15,
// row=(lane>>4)*4+reg [m89-verified]; A/B share the k-slot mapping.
// ---------------------------------------------------------------------------
template<int BM, bool A_BF16, bool RELU, int MMODE, bool ACCUM, bool OUT_BF16>
__global__ __launch_bounds__(256, 4)
void mfma16(const void* __restrict__ Av, const unsigned short* __restrict__ W16,
            const float* __restrict__ bias, const float* __restrict__ mask,
            const float* __restrict__ Caux, void* __restrict__ Cv, int N, int K)
{
    constexpr int LD = 72;              // 64 + 8 bf16 pad
    constexpr int FM = BM / 32;
    __shared__ unsigned short As[BM][LD];
    __shared__ unsigned short Bs[64][LD];

    const int tid  = threadIdx.x;
    const int lane = tid & 63;
    const int l15  = lane & 15;
    const int kg   = lane >> 4;
    const int w    = tid >> 6;
    const int wm   = w >> 1;
    const int wn   = w & 1;
    const int bm   = blockIdx.x * BM;
    const int bn   = blockIdx.y * 64;

    f32x4 acc[FM][2];
    #pragma unroll
    for (int i = 0; i < FM; ++i)
        #pragma unroll
        for (int j = 0; j < 2; ++j) acc[i][j] = (f32x4){0.f, 0.f, 0.f, 0.f};

    for (int k0 = 0; k0 < K; k0 += 64) {
        // ---- stage A (BM x 64) ----
        #pragma unroll
        for (int q = 0; q < BM / 32; ++q) {
            const int c    = tid + q * 256;
            const int row  = c >> 3;
            const int col8 = (c & 7) * 8;
            if (A_BF16) {
                const unsigned short* A = (const unsigned short*)Av;
                *(uint4*)&As[row][col8] =
                    *(const uint4*)(A + (size_t)(bm + row) * K + k0 + col8);
            } else {
                const float* A = (const float*)Av;
                const float4 v0 = *(const float4*)(A + (size_t)(bm + row) * K + k0 + col8);
                const float4 v1 = *(const float4*)(A + (size_t)(bm + row) * K + k0 + col8 + 4);
                uint4 pk;
                pk.x = (unsigned)f2bf(v0.x) | ((unsigned)f2bf(v0.y) << 16);
                pk.y = (unsigned)f2bf(v0.z) | ((unsigned)f2bf(v0.w) << 16);
                pk.z = (unsigned)f2bf(v1.x) | ((unsigned)f2bf(v1.y) << 16);
                pk.w = (unsigned)f2bf(v1.z) | ((unsigned)f2bf(v1.w) << 16);
                *(uint4*)&As[row][col8] = pk;
            }
        }
        // ---- stage B (64 x 64), pure bf16 copy ----
        #pragma unroll
        for (int q = 0; q < 2; ++q) {
            const int c    = tid + q * 256;
            const int row  = c >> 3;
            const int col8 = (c & 7) * 8;
            *(uint4*)&Bs[row][col8] =
                *(const uint4*)(W16 + (size_t)(bn + row) * K + k0 + col8);
        }
        __syncthreads();

        #pragma unroll
        for (int ksub = 0; ksub < 2; ++ksub) {
            s16x8 a[FM], bfr[2];
            #pragma unroll
            for (int fm = 0; fm < FM; ++fm)
                a[fm] = *(const s16x8*)&As[wm * (BM / 2) + fm * 16 + l15][ksub * 32 + kg * 8];
            #pragma unroll
            for (int fn = 0; fn < 2; ++fn)
                bfr[fn] = *(const s16x8*)&Bs[wn * 32 + fn * 16 + l15][ksub * 32 + kg * 8];
            #pragma unroll
            for (int fm = 0; fm < FM; ++fm)
                #pragma unroll
                for (int fn = 0; fn < 2; ++fn)
                    acc[fm][fn] = __builtin_amdgcn_mfma_f32_16x16x32_bf16(
                                      a[fm], bfr[fn], acc[fm][fn], 0, 0, 0);
        }
        __syncthreads();
    }

    // ---- epilogue ----
    #pragma unroll
    for (int fm = 0; fm < FM; ++fm) {
        #pragma unroll
        for (int fn = 0; fn < 2; ++fn) {
            const int col = bn + wn * 32 + fn * 16 + l15;
            #pragma unroll
            for (int r = 0; r < 4; ++r) {
                const int row = bm + wm * (BM / 2) + fm * 16 + kg * 4 + r;
                float v = acc[fm][fn][r] + bias[col];
                if (RELU) v = fmaxf(v, 0.f);
                if (MMODE == 1) v *= mask[row];
                if (MMODE == 2) v *= (1.f - mask[row]);
                const size_t o = (size_t)row * N + col;
                if (ACCUM) v += Caux[o];
                if (OUT_BF16) ((unsigned short*)Cv)[o] = f2bf(v);
                else          ((float*)Cv)[o] = v;
            }
        }
    }
}

// ---------------------------------------------------------------------------
// f32 VALU GEMM (head only): C = act(A @ W^T + b)
// ---------------------------------------------------------------------------
template<int BM, int BN, int TM, int TN, bool RELU>
__global__ __launch_bounds__(256, 2)
void gemm_kernel(const float* __restrict__ A, const float* __restrict__ W,
                 const float* __restrict__ bias, float* __restrict__ C,
                 int M, int N, int K)
{
    constexpr int BK  = 16;
    constexpr int LDA = BM + 4;
    constexpr int LDB = BN + 4;
    __shared__ float As[BK][LDA];
    __shared__ float Ws[BK][LDB];

    const int tid = threadIdx.x;
    const int tx = tid & 15;
    const int ty = tid >> 4;
    const int bm = blockIdx.x * BM;
    const int bn = blockIdx.y * BN;

    float acc[TM][TN];
    #pragma unroll
    for (int i = 0; i < TM; ++i)
        #pragma unroll
        for (int j = 0; j < TN; ++j) acc[i][j] = 0.f;

    constexpr int ACH = (BM * BK) / (4 * 256);
    constexpr int BCH = (BN * BK) / (4 * 256);

    for (int k0 = 0; k0 < K; k0 += BK) {
        #pragma unroll
        for (int q = 0; q < ACH; ++q) {
            const int c = tid + q * 256;
            const int m = c >> 2;
            const int kq = (c & 3) * 4;
            const float4 v = *(const float4*)&A[(size_t)(bm + m) * K + k0 + kq];
            As[kq + 0][m] = v.x; As[kq + 1][m] = v.y;
            As[kq + 2][m] = v.z; As[kq + 3][m] = v.w;
        }
        #pragma unroll
        for (int q = 0; q < BCH; ++q) {
            const int c = tid + q * 256;
            const int n = c >> 2;
            const int kq = (c & 3) * 4;
            float4 v = make_float4(0.f, 0.f, 0.f, 0.f);
            if (bn + n < N) v = *(const float4*)&W[(size_t)(bn + n) * K + k0 + kq];
            Ws[kq + 0][n] = v.x; Ws[kq + 1][n] = v.y;
            Ws[kq + 2][n] = v.z; Ws[kq + 3][n] = v.w;
        }
        __syncthreads();

        #pragma unroll
        for (int k = 0; k < BK; ++k) {
            float av[TM], bv[TN];
            {
                const float4 t0 = *(const float4*)&As[k][ty * TM];
                av[0] = t0.x; av[1] = t0.y; av[2] = t0.z; av[3] = t0.w;
            }
            {
                const float4 t0 = *(const float4*)&Ws[k][tx * TN];
                bv[0] = t0.x; bv[1] = t0.y; bv[2] = t0.z; bv[3] = t0.w;
            }
            #pragma unroll
            for (int i = 0; i < TM; ++i)
                #pragma unroll
                for (int j = 0; j < TN; ++j)
                    acc[i][j] = fmaf(av[i], bv[j], acc[i][j]);
        }
        __syncthreads();
    }

    #pragma unroll
    for (int i = 0; i < TM; ++i) {
        const int row = bm + ty * TM + i;
        #pragma unroll
        for (int j = 0; j < TN; ++j) {
            const int col = bn + tx * TN + j;
            if (col < N) {
                float v = acc[i][j] + bias[col];
                if (RELU) v = fmaxf(v, 0.f);
                C[(size_t)row * N + col] = v;
            }
        }
    }
}

// ---------------------------------------------------------------------------
extern "C" void kernel_launch(void* const* d_in, const int* in_sizes, int n_in,
                              void* d_out, int out_size, void* d_ws, size_t ws_size,
                              hipStream_t stream)
{
    (void)in_sizes; (void)n_in; (void)out_size; (void)ws_size;
    const float* images = (const float*)d_in[0];
    const float* patches= (const float*)d_in[1];
    const float* cw1 = (const float*)d_in[2];
    const float* cb1 = (const float*)d_in[3];
    const float* cw2 = (const float*)d_in[4];
    const float* cb2 = (const float*)d_in[5];
    const float* aw1 = (const float*)d_in[6];
    const float* ab1 = (const float*)d_in[7];
    const float* aw2 = (const float*)d_in[8];
    const float* ab2 = (const float*)d_in[9];
    const float* thr = (const float*)d_in[10];
    const float* bw1 = (const float*)d_in[11];
    const float* bb1 = (const float*)d_in[12];
    const float* bw2 = (const float*)d_in[13];
    const float* bb2 = (const float*)d_in[14];
    const float* bw3 = (const float*)d_in[15];
    const float* bb3 = (const float*)d_in[16];
    const float* bwo = (const float*)d_in[17];
    const float* bbo = (const float*)d_in[18];
    const float* sw1 = (const float*)d_in[19];
    const float* sb1 = (const float*)d_in[20];
    const float* swo = (const float*)d_in[21];
    const float* sbo = (const float*)d_in[22];
    const float* gw  = (const float*)d_in[23];
    const float* gb  = (const float*)d_in[24];
    const float* hw1 = (const float*)d_in[25];
    const float* hb1 = (const float*)d_in[26];
    const float* hw2 = (const float*)d_in[27];
    const float* hb2 = (const float*)d_in[28];
    float* out = (float*)d_out;
    float* ws  = (float*)d_ws;

    // workspace layout: ~30.2 MB (r1 proved >= 36.8 MB available)
    float* mask = ws;                                        // 8192 f32
    float* CMBf = ws + 8192;                                 // 8192*128 f32
    float* G    = CMBf + 8192 * 128;                         // 512*256 f32
    float* T    = G + 512 * 256;                             // 512*128 f32
    unsigned short* X1   = (unsigned short*)(T + 512 * 128); // 8192*512 bf16
    unsigned short* X2   = X1 + 8192 * 512;                  // 8192*512 bf16
    unsigned short* S16  = X2 + 8192 * 512;                  // 8192*64  bf16
    unsigned short* CMB16= S16 + 8192 * 64;                  // 8192*128 bf16
    unsigned short* w1_16= CMB16 + 8192 * 128;               // 512*3072
    unsigned short* w2_16= w1_16 + 512 * 3072;               // 512*512
    unsigned short* w3_16= w2_16 + 512 * 512;                // 512*512
    unsigned short* wo_16= w3_16 + 512 * 512;                // 128*512
    unsigned short* s1_16= wo_16 + 128 * 512;                // 64*3072
    unsigned short* so_16= s1_16 + 64 * 3072;                // 128*64
    unsigned short* gw_16= so_16 + 128 * 64;                 // 256*2048

    // ---- weights pre-conversion (one launch, 7 segments) ----
    CvtArgs ca;
    ca.seg[0] = { bw1, w1_16, 512 * 3072 };
    ca.seg[1] = { bw2, w2_16, 512 * 512 };
    ca.seg[2] = { bw3, w3_16, 512 * 512 };
    ca.seg[3] = { bwo, wo_16, 128 * 512 };
    ca.seg[4] = { sw1, s1_16, 64 * 3072 };
    ca.seg[5] = { swo, so_16, 128 * 64 };
    ca.seg[6] = { gw,  gw_16, 256 * 2048 };
    cvt_kernel<<<dim3(768, 7), 256, 0, stream>>>(ca);

    // ---- router mask (exact f32 score chain) ----
    conv_attn_kernel<<<8192, 256, 0, stream>>>(images, cw1, cb1, cw2, cb2,
                                               aw1, ab1, aw2, ab2, thr, mask);

    // ---- big MLP (bf16 MFMA): pf -> 512 -> 512 -> 512 -> 128 (masked) ----
    mfma16<64,false,true ,0,false,true ><<<dim3(128,8), 256, 0, stream>>>(patches, w1_16, bb1, nullptr, nullptr, X1,  512, 3072);
    mfma16<64,true ,true ,0,false,true ><<<dim3(128,8), 256, 0, stream>>>(X1,      w2_16, bb2, nullptr, nullptr, X2,  512, 512);
    mfma16<64,true ,true ,0,false,true ><<<dim3(128,8), 256, 0, stream>>>(X2,      w3_16, bb3, nullptr, nullptr, X1,  512, 512);
    mfma16<32,true ,false,1,false,false><<<dim3(256,2), 256, 0, stream>>>(X1,      wo_16, bbo, mask,    nullptr, CMBf, 128, 512);

    // ---- small MLP: pf -> 64 -> 128, (1-mask), + CMBf -> CMB16 (bf16) ----
    mfma16<32,false,true ,0,false,true ><<<dim3(256,1), 256, 0, stream>>>(patches, s1_16, sb1, nullptr, nullptr, S16, 64, 3072);
    mfma16<32,true ,false,2,true ,true ><<<dim3(256,2), 256, 0, stream>>>(S16,     so_16, sbo, mask,    CMBf,    CMB16, 128, 64);

    // ---- aggregator (512,2048)->256 via MFMA; head in f32 ----
    mfma16<64,true ,false,0,false,false><<<dim3(8,4),   256, 0, stream>>>(CMB16,   gw_16, gb,  nullptr, nullptr, G, 256, 2048);
    gemm_kernel<64,64,4,4,true ><<<dim3(8,2), 256, 0, stream>>>(G, hw1, hb1, T,   512, 128, 256);
    gemm_kernel<64,64,4,4,false><<<dim3(8,1), 256, 0, stream>>>(T, hw2, hb2, out, 512, 10,  128);
}